// Round 6
// baseline (69.879 us; speedup 1.0000x reference)
//
#include <hip/hip_runtime.h>
#include <math.h>

// Chamfer distance: B=16, N=M=2048, D=3, fp32. Fused main kernel + tiny reduce.
// R5 post-mortem: prologue vectorization is null -> prologue off critical path.
// Per-CU pipe model of the main loop: VALU 8192 cyc vs LDS 1024 ds_read_b128
//   x ~12 cyc = 12288 cyc -> LDS-read pipe is the binding resource (unless
//   broadcast is discounted). This round halves LDS reads: SPT 8->16,
//   OPPT 64->32 (same 512 pairs/thread, same 2 VALU inst/pair). Per-wave
//   reads now 16 distinct addrs -> 8 bank-offsets x 4 banks = all 32 banks,
//   worst 2-way aliasing (free, m136). nn[16] = 96 VGPR; __launch_bounds__
//   (256,3) caps alloc at 170 (no spill at ~140 live, guarantees 12 waves/CU).
//   Src gather in 4 progressive rounds of {3 float4 loads -> 4 static
//   deswizzles} to bound staging pressure. Opp staging + sum kernel = R5.
// Block = (combo, 64-src chunk), 1024 blocks; q = tid>>2 scans opp
//   [32q,32q+32), c = tid&3 owns src pts c*16..c*16+15.

typedef float v2f __attribute__((ext_vector_type(2)));

#define NPTS   2048
#define NCOMBO 32          // 2 dirs x 16 batches
#define SRCB   64          // src points per block
#define SPT    16          // src points per thread
#define OPPT   32          // opp points scanned per thread
#define NBLK   (NCOMBO * 32)
#define PAD(i) ((i) + (((i) >> 6) << 2))   // +4 words per 64 -> bank spread

__device__ __forceinline__ v2f pkfma(v2f a, v2f b, v2f c) {
#if __has_builtin(__builtin_elementwise_fma)
    return __builtin_elementwise_fma(a, b, c);
#else
    v2f d; d.x = fmaf(a.x, b.x, c.x); d.y = fmaf(a.y, b.y, c.y); return d;
#endif
}

__global__ __launch_bounds__(256, 3) void chamfer_fused(
    const float* __restrict__ preds,
    const float* __restrict__ tgts,
    float* __restrict__ bsum)
{
    __shared__ __align__(16) float qx[2176];   // 2048 + 128 pad words
    __shared__ __align__(16) float qy[2176];
    __shared__ __align__(16) float qz[2176];
    __shared__ __align__(16) float qw[2176];
    __shared__ float sm[4 * SRCB];             // per-wave partial minima

    const int combo = blockIdx.x & (NCOMBO - 1);
    const int chunk = blockIdx.x >> 5;         // 0..31
    const int dir   = combo >> 4;
    const int b     = combo & 15;

    const float* src = (dir ? tgts : preds) + (size_t)b * NPTS * 3;
    const float* opp = (dir ? preds : tgts) + (size_t)b * NPTS * 3;

    // Stage all 2048 opposing points (SoA, padded; |y|^2 in qw).
    // 3 float4 loads = 4 interleaved xyz points, STATIC deswizzle (no scratch).
    const float4* opp4 = (const float4*)opp;
    #pragma unroll
    for (int p = 0; p < 2; p++) {
        const int t  = threadIdx.x + 256 * p;   // pts 4t..4t+3
        const float4 A = opp4[3 * t + 0];       // x0 y0 z0 x1
        const float4 B = opp4[3 * t + 1];       // y1 z1 x2 y2
        const float4 C = opp4[3 * t + 2];       // z2 x3 y3 z3
        const int i0 = 4 * t;
        {   const int pi = PAD(i0 + 0);
            qx[pi] = A.x; qy[pi] = A.y; qz[pi] = A.z;
            qw[pi] = A.x * A.x + A.y * A.y + A.z * A.z; }
        {   const int pi = PAD(i0 + 1);
            qx[pi] = A.w; qy[pi] = B.x; qz[pi] = B.y;
            qw[pi] = A.w * A.w + B.x * B.x + B.y * B.y; }
        {   const int pi = PAD(i0 + 2);
            qx[pi] = B.z; qy[pi] = B.w; qz[pi] = C.x;
            qw[pi] = B.z * B.z + B.w * B.w + C.x * C.x; }
        {   const int pi = PAD(i0 + 3);
            qx[pi] = C.y; qy[pi] = C.z; qz[pi] = C.w;
            qw[pi] = C.y * C.y + C.z * C.z + C.w * C.w; }
    }

    const int q = threadIdx.x >> 2;   // opp range [32q, 32q+32), 0..63
    const int c = threadIdx.x & 3;    // src ownership group, 0..3

    // 16 consecutive src points = 48 floats = 12 aligned float4 loads, in 4
    // progressive rounds (3 loads -> 4 static deswizzles) to bound pressure.
    v2f nn0[SPT], nn1[SPT], nn2[SPT];
    float m[SPT];
    const float4* s4 = (const float4*)(src + 3 * (chunk * SRCB + c * SPT));
    #pragma unroll
    for (int p = 0; p < 4; p++) {
        const float4 A = s4[3 * p + 0];         // x0 y0 z0 x1
        const float4 B = s4[3 * p + 1];         // y1 z1 x2 y2
        const float4 C = s4[3 * p + 2];         // z2 x3 y3 z3
        const int k0 = 4 * p;
        {   const float a0 = -2.0f * A.x, a1 = -2.0f * A.y, a2 = -2.0f * A.z;
            nn0[k0+0] = (v2f){a0, a0}; nn1[k0+0] = (v2f){a1, a1}; nn2[k0+0] = (v2f){a2, a2}; }
        {   const float a0 = -2.0f * A.w, a1 = -2.0f * B.x, a2 = -2.0f * B.y;
            nn0[k0+1] = (v2f){a0, a0}; nn1[k0+1] = (v2f){a1, a1}; nn2[k0+1] = (v2f){a2, a2}; }
        {   const float a0 = -2.0f * B.z, a1 = -2.0f * B.w, a2 = -2.0f * C.x;
            nn0[k0+2] = (v2f){a0, a0}; nn1[k0+2] = (v2f){a1, a1}; nn2[k0+2] = (v2f){a2, a2}; }
        {   const float a0 = -2.0f * C.y, a1 = -2.0f * C.z, a2 = -2.0f * C.w;
            nn0[k0+3] = (v2f){a0, a0}; nn1[k0+3] = (v2f){a1, a1}; nn2[k0+3] = (v2f){a2, a2}; }
    }
    #pragma unroll
    for (int k = 0; k < SPT; k++) m[k] = INFINITY;
    __syncthreads();

    const int base = PAD(q * 32);     // 16B-aligned; pad constant over range
    #pragma unroll 1
    for (int g = 0; g < OPPT / 4; g++) {
        const float4 X = *(const float4*)&qx[base + 4 * g];
        const float4 Y = *(const float4*)&qy[base + 4 * g];
        const float4 Z = *(const float4*)&qz[base + 4 * g];
        const float4 W = *(const float4*)&qw[base + 4 * g];
        const v2f Xa = {X.x, X.y}, Xb = {X.z, X.w};
        const v2f Ya = {Y.x, Y.y}, Yb = {Y.z, Y.w};
        const v2f Za = {Z.x, Z.y}, Zb = {Z.z, Z.w};
        const v2f Wa = {W.x, W.y}, Wb = {W.z, W.w};
        #pragma unroll
        for (int k = 0; k < SPT; k++) {
            const v2f sa = pkfma(nn0[k], Xa, pkfma(nn1[k], Ya, pkfma(nn2[k], Za, Wa)));
            m[k] = fminf(fminf(m[k], sa.x), sa.y);        // v_min3_f32
            const v2f sb = pkfma(nn0[k], Xb, pkfma(nn1[k], Yb, pkfma(nn2[k], Zb, Wb)));
            m[k] = fminf(fminf(m[k], sb.x), sb.y);        // v_min3_f32
        }
    }

    // Min over the 64 q-groups: 16 in-wave q's via shfl_xor (bits 2..5 of
    // lane), then the 4 waves via 1KB LDS.
    #pragma unroll
    for (int k = 0; k < SPT; k++) {
        float v = m[k];
        v = fminf(v, __shfl_xor(v, 4, 64));
        v = fminf(v, __shfl_xor(v, 8, 64));
        v = fminf(v, __shfl_xor(v, 16, 64));
        v = fminf(v, __shfl_xor(v, 32, 64));
        m[k] = v;
    }
    const int lane = threadIdx.x & 63;
    const int wid  = threadIdx.x >> 6;
    if (lane < 4) {
        #pragma unroll
        for (int k = 0; k < SPT; k++)
            sm[wid * SRCB + lane * SPT + k] = m[k];
    }
    __syncthreads();

    // Wave 0: finalize 64 src minima, add |x|^2, block-sum, ONE plain store.
    if (threadIdx.x < 64) {
        const int off = threadIdx.x;              // = c*SPT + k
        float mn = fminf(fminf(sm[off],            sm[SRCB + off]),
                         fminf(sm[2 * SRCB + off], sm[3 * SRCB + off]));
        const int s = chunk * SRCB + off;
        const float x0 = src[3 * s + 0];
        const float x1 = src[3 * s + 1];
        const float x2 = src[3 * s + 2];
        float val = x0 * x0 + x1 * x1 + x2 * x2 + mn;
        #pragma unroll
        for (int o = 32; o > 0; o >>= 1)
            val += __shfl_down(val, o, 64);
        if (threadIdx.x == 0) bsum[blockIdx.x] = val;
    }
}

__global__ __launch_bounds__(256) void chamfer_sum(
    const float* __restrict__ bsum,
    float* __restrict__ out)
{
    __shared__ float wsum[4];

    float val = bsum[threadIdx.x]         + bsum[threadIdx.x + 256]
              + bsum[threadIdx.x + 512]   + bsum[threadIdx.x + 768];

    #pragma unroll
    for (int o = 32; o > 0; o >>= 1)
        val += __shfl_down(val, o, 64);

    const int lane = threadIdx.x & 63;
    const int wid  = threadIdx.x >> 6;
    if (lane == 0) wsum[wid] = val;
    __syncthreads();
    if (threadIdx.x == 0)
        out[0] = wsum[0] + wsum[1] + wsum[2] + wsum[3];
}

extern "C" void kernel_launch(void* const* d_in, const int* in_sizes, int n_in,
                              void* d_out, int out_size, void* d_ws, size_t ws_size,
                              hipStream_t stream) {
    const float* preds = (const float*)d_in[0];
    const float* tgts  = (const float*)d_in[1];
    float* out  = (float*)d_out;
    float* bsum = (float*)d_ws;   // 1024 floats

    chamfer_fused<<<NBLK, 256, 0, stream>>>(preds, tgts, bsum);
    chamfer_sum<<<1, 256, 0, stream>>>(bsum, out);
}

// Round 8
// 67.055 us; speedup vs baseline: 1.0421x; 1.0421x over previous
//
#include <hip/hip_runtime.h>
#include <math.h>

// Chamfer distance: B=16, N=M=2048, D=3, fp32. Fused main kernel + tiny reduce.
// R6 post-mortem: SPT=16 (+3 blocks/CU only) regressed +4.2us -> LDS-read
//   throughput is NOT the binding pipe; occupancy is. This round returns to
//   the best-measured R3 frame (SPT=8, scalar prologues, unroll 1) and buys a
//   5th resident block/CU by shrinking LDS to exactly 32768 B:
//   - padding removed; bank spread instead via read-order ROTATION inside each
//     q-window: o = base + ((4g + 4(q&7)) & 63). Min is order-independent;
//     float4 reads stay 16B-aligned; for fixed g the wave's 8 q-groups hit
//     banks (4g+4q)%32 -> 8 starts x 4 words = all 32 banks, conflict-free,
//     zero space.
//   - sm (256 floats) aliased into qx after the main loop (qx dead; one extra
//     __syncthreads before overwrite).
//   4 -> 5 blocks/CU (16 -> 20 waves/CU): more latency hiding for the same
//   instruction stream.
// (R7: identical resubmit — container infra failure, no data.)
// Block = (combo, 64-src chunk), 1024 blocks; q = tid>>3 scans opp
//   [64q,64q+64) rotated, c = tid&7 owns src pts c*8..c*8+7.

typedef float v2f __attribute__((ext_vector_type(2)));

#define NPTS   2048
#define NCOMBO 32          // 2 dirs x 16 batches
#define SRCB   64          // src points per block
#define SPT    8           // src points per thread
#define OPPT   64          // opp points scanned per thread
#define NBLK   (NCOMBO * 32)

__device__ __forceinline__ v2f pkfma(v2f a, v2f b, v2f c) {
#if __has_builtin(__builtin_elementwise_fma)
    return __builtin_elementwise_fma(a, b, c);
#else
    v2f d; d.x = fmaf(a.x, b.x, c.x); d.y = fmaf(a.y, b.y, c.y); return d;
#endif
}

__global__ __launch_bounds__(256, 2) void chamfer_fused(
    const float* __restrict__ preds,
    const float* __restrict__ tgts,
    float* __restrict__ bsum)
{
    // Exactly 32768 B of LDS -> 5 blocks/CU (160 KiB / 32 KiB = 5).
    __shared__ __align__(16) float qx[2048];
    __shared__ __align__(16) float qy[2048];
    __shared__ __align__(16) float qz[2048];
    __shared__ __align__(16) float qw[2048];

    const int combo = blockIdx.x & (NCOMBO - 1);
    const int chunk = blockIdx.x >> 5;         // 0..31
    const int dir   = combo >> 4;
    const int b     = combo & 15;

    const float* src = (dir ? tgts : preds) + (size_t)b * NPTS * 3;
    const float* opp = (dir ? preds : tgts) + (size_t)b * NPTS * 3;

    // Stage all 2048 opposing points (SoA, unpadded; |y|^2 in qw).
    // Writes: lanes hit consecutive words -> 2-way bank aliasing (free).
    #pragma unroll
    for (int p = 0; p < NPTS / 256; p++) {
        const int i = threadIdx.x + 256 * p;
        const float y0 = opp[3 * i + 0];
        const float y1 = opp[3 * i + 1];
        const float y2 = opp[3 * i + 2];
        qx[i] = y0;
        qy[i] = y1;
        qz[i] = y2;
        qw[i] = y0 * y0 + y1 * y1 + y2 * y2;
    }

    const int q = threadIdx.x >> 3;   // opp window [64q, 64q+64)
    const int c = threadIdx.x & 7;    // src ownership group

    // 8 src points per thread; nn = -2*x duplicated for packed math
    v2f nn0[SPT], nn1[SPT], nn2[SPT];
    float m[SPT];
    #pragma unroll
    for (int k = 0; k < SPT; k++) {
        const int s = chunk * SRCB + c * SPT + k;
        const float a0 = -2.0f * src[3 * s + 0];
        const float a1 = -2.0f * src[3 * s + 1];
        const float a2 = -2.0f * src[3 * s + 2];
        nn0[k] = (v2f){a0, a0};
        nn1[k] = (v2f){a1, a1};
        nn2[k] = (v2f){a2, a2};
        m[k]   = INFINITY;
    }
    __syncthreads();

    const int base = q * 64;
    const int rot  = (q & 7) << 2;    // rotation in floats: 0,4,...,28
    #pragma unroll 1
    for (int g = 0; g < OPPT / 4; g++) {
        const int o = base + ((4 * g + rot) & 63);   // 16B-aligned, in-window
        const float4 X = *(const float4*)&qx[o];
        const float4 Y = *(const float4*)&qy[o];
        const float4 Z = *(const float4*)&qz[o];
        const float4 W = *(const float4*)&qw[o];
        const v2f Xa = {X.x, X.y}, Xb = {X.z, X.w};
        const v2f Ya = {Y.x, Y.y}, Yb = {Y.z, Y.w};
        const v2f Za = {Z.x, Z.y}, Zb = {Z.z, Z.w};
        const v2f Wa = {W.x, W.y}, Wb = {W.z, W.w};
        #pragma unroll
        for (int k = 0; k < SPT; k++) {
            const v2f sa = pkfma(nn0[k], Xa, pkfma(nn1[k], Ya, pkfma(nn2[k], Za, Wa)));
            m[k] = fminf(fminf(m[k], sa.x), sa.y);        // v_min3_f32
            const v2f sb = pkfma(nn0[k], Xb, pkfma(nn1[k], Yb, pkfma(nn2[k], Zb, Wb)));
            m[k] = fminf(fminf(m[k], sb.x), sb.y);        // v_min3_f32
        }
    }

    // Min over the 32 q-groups: 8 in-wave q's via shfl_xor (bits 3..5 of lane),
    // then the 4 waves via LDS (sm aliases qx -- dead after the main loop).
    #pragma unroll
    for (int k = 0; k < SPT; k++) {
        float v = m[k];
        v = fminf(v, __shfl_xor(v, 8, 64));
        v = fminf(v, __shfl_xor(v, 16, 64));
        v = fminf(v, __shfl_xor(v, 32, 64));
        m[k] = v;
    }
    __syncthreads();                  // all main-loop LDS reads done
    float* sm = qx;                   // reuse qx storage (256 floats needed)
    const int lane = threadIdx.x & 63;
    const int wid  = threadIdx.x >> 6;
    if (lane < 8) {
        #pragma unroll
        for (int k = 0; k < SPT; k++)
            sm[wid * SRCB + c * SPT + k] = m[k];
    }
    __syncthreads();

    // Wave 0: finalize 64 src minima, add |x|^2, block-sum, ONE plain store.
    if (threadIdx.x < 64) {
        const int off = (threadIdx.x & 7) * SPT + (threadIdx.x >> 3);
        float mn = fminf(fminf(sm[off],            sm[SRCB + off]),
                         fminf(sm[2 * SRCB + off], sm[3 * SRCB + off]));
        const int s = chunk * SRCB + off;
        const float x0 = src[3 * s + 0];
        const float x1 = src[3 * s + 1];
        const float x2 = src[3 * s + 2];
        float val = x0 * x0 + x1 * x1 + x2 * x2 + mn;
        #pragma unroll
        for (int o = 32; o > 0; o >>= 1)
            val += __shfl_down(val, o, 64);
        if (threadIdx.x == 0) bsum[blockIdx.x] = val;
    }
}

__global__ __launch_bounds__(256) void chamfer_sum(
    const float* __restrict__ bsum,
    float* __restrict__ out)
{
    __shared__ float wsum[4];

    float val = bsum[threadIdx.x]         + bsum[threadIdx.x + 256]
              + bsum[threadIdx.x + 512]   + bsum[threadIdx.x + 768];

    #pragma unroll
    for (int o = 32; o > 0; o >>= 1)
        val += __shfl_down(val, o, 64);

    const int lane = threadIdx.x & 63;
    const int wid  = threadIdx.x >> 6;
    if (lane == 0) wsum[wid] = val;
    __syncthreads();
    if (threadIdx.x == 0)
        out[0] = wsum[0] + wsum[1] + wsum[2] + wsum[3];
}

extern "C" void kernel_launch(void* const* d_in, const int* in_sizes, int n_in,
                              void* d_out, int out_size, void* d_ws, size_t ws_size,
                              hipStream_t stream) {
    const float* preds = (const float*)d_in[0];
    const float* tgts  = (const float*)d_in[1];
    float* out  = (float*)d_out;
    float* bsum = (float*)d_ws;   // 1024 floats

    chamfer_fused<<<NBLK, 256, 0, stream>>>(preds, tgts, bsum);
    chamfer_sum<<<1, 256, 0, stream>>>(bsum, out);
}